// Round 21
// baseline (1160.264 us; speedup 1.0000x reference)
//
#include <hip/hip_runtime.h>
#include <hip/hip_bf16.h>

#define NROWS 32768
#define DIM   512
#define NQ    8
#define NBINS 2048

#define MARGIN 5.0f        // ~7 sigma of i8 phase-1 dist-DIFF noise (validated r18-r20)
#define CSLOT  520         // floats per candidate LDS slot (2080B, 16B-aligned)

typedef __attribute__((ext_vector_type(4))) float f32x4;
typedef __attribute__((ext_vector_type(4))) int i32x4;

typedef __attribute__((address_space(3))) void lds_t;
typedef __attribute__((address_space(1))) const void gbl_t;
__device__ inline void gload16(const void* g, void* l) {
    __builtin_amdgcn_global_load_lds((gbl_t*)g, (lds_t*)l, 16, 0, 0);
}

// ---------------------------------------------------------------------------
// numpy pairwise-sum combine (validated round 4)
__device__ inline float pw_combine(float s) {
#pragma unroll
    for (int m = 1; m <= 16; m <<= 1) {
        float o = __shfl_xor(s, m, 64);
        s = __fadd_rn(s, o);
    }
    return s;
}

// deterministic f32 -> i8 (RNE, clamp +-127), packed low byte
__device__ inline int q8(float v, float qs) {
    float x = fminf(fmaxf(v * qs, -127.0f), 127.0f);
    return __float2int_rn(x) & 255;
}
__device__ inline int pack4(float a, float b, float c, float d, float qs) {
    return q8(a, qs) | (q8(b, qs) << 8) | (q8(c, qs) << 16) | (q8(d, qs) << 24);
}

// ---------------------------------------------------------------------------
// fused prep: codebook fp32 -> i8 (per-bin scale) AND np-exact csq (validated r4/r16).
__global__ __launch_bounds__(256) void k_prep(const float* __restrict__ cb,
                                              unsigned char* __restrict__ o,
                                              float* __restrict__ csq32,
                                              float* __restrict__ sclc) {
    int row = blockIdx.x * 4 + (threadIdx.x >> 6);
    int lane = threadIdx.x & 63;
    const float* cp = cb + (size_t)row * DIM;

    float4 a = *(const float4*)(cp + lane * 8);
    float4 b = *(const float4*)(cp + lane * 8 + 4);

    float mx = fmaxf(fmaxf(fmaxf(fabsf(a.x), fabsf(a.y)), fmaxf(fabsf(a.z), fabsf(a.w))),
                     fmaxf(fmaxf(fabsf(b.x), fabsf(b.y)), fmaxf(fabsf(b.z), fabsf(b.w))));
#pragma unroll
    for (int m2 = 32; m2 > 0; m2 >>= 1) mx = fmaxf(mx, __shfl_xor(mx, m2));
    float qs = (mx > 0.0f) ? 127.0f / mx : 0.0f;

    int2 pv;
    pv.x = pack4(a.x, a.y, a.z, a.w, qs);
    pv.y = pack4(b.x, b.y, b.z, b.w, qs);
    *(int2*)(o + (size_t)row * DIM + lane * 8) = pv;

    float s = 0.0f;
    if (lane < 32) {
        int base = (lane >> 3) * 128 + (lane & 7);
        float e = cp[base];
        s = __fmul_rn(e, e);
#pragma unroll
        for (int m = 1; m < 16; ++m) {
            float e2 = cp[base + 8 * m];
            s = __fadd_rn(s, __fmul_rn(e2, e2));
        }
    }
    s = pw_combine(s);
    if (lane == 0) {
        csq32[row] = s;
        sclc[row] = (mx > 0.0f) ? mx / 127.0f : 0.0f;
    }
}

// ---------------------------------------------------------------------------
// initial residual (= hidden) + np-exact rsq + i8 copy (per-row scale).
__global__ __launch_bounds__(256) void k_init(const float* __restrict__ h,
                                              float* __restrict__ rout,
                                              float* __restrict__ rsq,
                                              unsigned char* __restrict__ a8,
                                              float* __restrict__ sclr) {
    int row = blockIdx.x * 4 + (threadIdx.x >> 6);
    int w = threadIdx.x >> 6;
    int lane = threadIdx.x & 63;
    __shared__ float sq[4][DIM];

    const float* hp = h + (size_t)row * DIM + lane * 8;
    float4 r0 = *(const float4*)hp;
    float4 r1 = *(const float4*)(hp + 4);
    float* wp = rout + (size_t)row * DIM + lane * 8;
    *(float4*)wp = r0;
    *(float4*)(wp + 4) = r1;

    float mx = fmaxf(fmaxf(fmaxf(fabsf(r0.x), fabsf(r0.y)), fmaxf(fabsf(r0.z), fabsf(r0.w))),
                     fmaxf(fmaxf(fabsf(r1.x), fabsf(r1.y)), fmaxf(fabsf(r1.z), fabsf(r1.w))));
#pragma unroll
    for (int m2 = 32; m2 > 0; m2 >>= 1) mx = fmaxf(mx, __shfl_xor(mx, m2));
    float qs = (mx > 0.0f) ? 127.0f / mx : 0.0f;
    int2 pv;
    pv.x = pack4(r0.x, r0.y, r0.z, r0.w, qs);
    pv.y = pack4(r1.x, r1.y, r1.z, r1.w, qs);
    *(int2*)(a8 + (size_t)row * DIM + lane * 8) = pv;
    if (lane == 0) sclr[row] = (mx > 0.0f) ? mx / 127.0f : 0.0f;

    sq[w][lane * 8 + 0] = __fmul_rn(r0.x, r0.x);
    sq[w][lane * 8 + 1] = __fmul_rn(r0.y, r0.y);
    sq[w][lane * 8 + 2] = __fmul_rn(r0.z, r0.z);
    sq[w][lane * 8 + 3] = __fmul_rn(r0.w, r0.w);
    sq[w][lane * 8 + 4] = __fmul_rn(r1.x, r1.x);
    sq[w][lane * 8 + 5] = __fmul_rn(r1.y, r1.y);
    sq[w][lane * 8 + 6] = __fmul_rn(r1.z, r1.z);
    sq[w][lane * 8 + 7] = __fmul_rn(r1.w, r1.w);
    __syncthreads();
    if (lane < 32) {
        int base = (lane >> 3) * 128 + (lane & 7);
        float s = sq[w][base];
#pragma unroll
        for (int m = 1; m < 16; ++m) s = __fadd_rn(s, sq[w][base + 8 * m]);
        s = pw_combine(s);
        if (lane == 0) rsq[row] = s;
    }
}

// ---------------------------------------------------------------------------
// phase-1: i8 MFMA GEMM (validated r20, byte-identical): r16 math/layout,
// r19 dbuf staging, r20 stride-68 conflict-free epilogue.
__global__ __launch_bounds__(256, 4) void k_gemm(const unsigned char* __restrict__ A8,
                                                 const unsigned char* __restrict__ B8,
                                                 const float* __restrict__ csq,
                                                 const float* __restrict__ sclr,
                                                 const float* __restrict__ sclc,
                                                 float* __restrict__ partD,   // [NROWS][64]
                                                 int* __restrict__ partI) {
    __shared__ __align__(16) char lds[34816];   // dbuf 2x(A8K|B8K)=32K ; dist [128][68] f32
    __shared__ float csqS[128], sclcS[128], sclrS[128];

    const int tid = threadIdx.x;
    const int lane = tid & 63;
    const int w = tid >> 6;
    const int wr = w >> 1;
    const int wc = w & 1;

    // L2-chunked XCD decode (validated r15/r16)
    const int wg = blockIdx.x;
    const int seq = wg >> 3;
    const int panel = (wg & 7) * 32 + (seq >> 8) * 16 + (seq & 15);
    const int T = (seq >> 4) & 15;

    if (tid < 128) {
        csqS[tid] = csq[T * 128 + tid];
        sclcS[tid] = sclc[T * 128 + tid];
        sclrS[tid] = sclr[panel * 128 + tid];
    }

    const char* Abase = (const char*)(A8 + (size_t)panel * 128 * DIM);
    const char* Bbase = (const char*)(B8 + (size_t)T * 128 * DIM);

    int goff[2], loff[2];
#pragma unroll
    for (int i = 0; i < 2; ++i) {
        int L = i * 256 + tid;
        int row = L >> 2, cc = L & 3;
        goff[i] = row * DIM + ((cc ^ ((row >> 1) & 3)) << 4);
        loff[i] = L * 16;
    }

    i32x4 acc[4][4];
#pragma unroll
    for (int m = 0; m < 4; ++m)
#pragma unroll
        for (int n = 0; n < 4; ++n) acc[m][n] = (i32x4){0, 0, 0, 0};

    const int arow = lane & 15;
    const int slot = ((lane >> 4) ^ ((arow >> 1) & 3)) << 4;

    // prologue: stage tile 0 into buf 0
#pragma unroll
    for (int i = 0; i < 2; ++i) {
        gload16(Abase + goff[i], lds + loff[i]);
        gload16(Bbase + goff[i], lds + 8192 + loff[i]);
    }
    __syncthreads();

#pragma unroll
    for (int ks = 0; ks < 8; ++ks) {
        if (ks < 7) {                          // issue next tile early (flies under MFMA)
            char* buf = lds + ((ks + 1) & 1) * 16384;
            const int k0b = (ks + 1) * 64;
#pragma unroll
            for (int i = 0; i < 2; ++i) {
                gload16(Abase + goff[i] + k0b, buf + loff[i]);
                gload16(Bbase + goff[i] + k0b, buf + 8192 + loff[i]);
            }
        }
        const char* Ab = lds + (ks & 1) * 16384;
        const char* Bb = Ab + 8192;
        __builtin_amdgcn_s_setprio(1);
        i32x4 bF[4];
#pragma unroll
        for (int n = 0; n < 4; ++n)
            bF[n] = *(const i32x4*)(Bb + (wc * 64 + n * 16 + arow) * 64 + slot);
#pragma unroll
        for (int m = 0; m < 4; ++m) {
            i32x4 aF = *(const i32x4*)(Ab + (wr * 64 + m * 16 + arow) * 64 + slot);
#pragma unroll
            for (int n = 0; n < 4; ++n)
                acc[m][n] = __builtin_amdgcn_mfma_i32_16x16x64_i8(
                    aF, bF[n], acc[m][n], 0, 0, 0);
        }
        __builtin_amdgcn_s_setprio(0);
        __syncthreads();   // tile ks reads done by all waves + tile ks+1 resident
    }

    // --- r20 epilogue (validated): stride-68, float4 scan, hoisted scales ---
    float* distf = (float*)lds;
    const int row2 = tid >> 1, h = tid & 1;

    float rowsc[16];
#pragma unroll
    for (int m = 0; m < 4; ++m)
#pragma unroll
        for (int r = 0; r < 4; ++r)
            rowsc[m * 4 + r] = 2.0f * sclrS[wr * 64 + m * 16 + (lane >> 4) * 4 + r];

    float td0 = 3.4e38f, td1 = 3.4e38f, td2 = 3.4e38f, td3 = 3.4e38f;
    int ti0 = 0, ti1 = 0, ti2 = 0, ti3 = 0;

#pragma unroll
    for (int p = 0; p < 2; ++p) {
        float csq4[4], sclc4[4];
#pragma unroll
        for (int n = 0; n < 4; ++n) {
            csq4[n] = csqS[p * 64 + n * 16 + (lane & 15)];
            sclc4[n] = sclcS[p * 64 + n * 16 + (lane & 15)];
        }
        __syncthreads();
        if (wc == p) {
#pragma unroll
            for (int m = 0; m < 4; ++m)
#pragma unroll
                for (int n = 0; n < 4; ++n)
#pragma unroll
                    for (int r = 0; r < 4; ++r) {
                        int row = wr * 64 + m * 16 + (lane >> 4) * 4 + r;
                        int cl = n * 16 + (lane & 15);
                        distf[row * 68 + cl] =
                            csq4[n] - (float)acc[m][n][r] * (rowsc[m * 4 + r] * sclc4[n]);
                    }
        }
        __syncthreads();
        int binb = T * 128 + p * 64 + h * 32;
        const float* rowp = &distf[row2 * 68 + h * 32];
#pragma unroll
        for (int c4 = 0; c4 < 8; ++c4) {
            float4 v = *(const float4*)(rowp + c4 * 4);
#pragma unroll
            for (int j = 0; j < 4; ++j) {
                float d = (j == 0) ? v.x : (j == 1) ? v.y : (j == 2) ? v.z : v.w;
                int bin = binb + c4 * 4 + j;
                if (d < td3) {
                    if (d < td2) {
                        td3 = td2; ti3 = ti2;
                        if (d < td1) {
                            td2 = td1; ti2 = ti1;
                            if (d < td0) { td1 = td0; ti1 = ti0; td0 = d; ti0 = bin; }
                            else { td1 = d; ti1 = bin; }
                        } else { td2 = d; ti2 = bin; }
                    } else { td3 = d; ti3 = bin; }
                }
            }
        }
    }
#pragma unroll
    for (int j = 0; j < 4; ++j) {
        float d = __shfl_xor(j == 0 ? td0 : (j == 1 ? td1 : (j == 2 ? td2 : td3)), 1);
        int bin = __shfl_xor(j == 0 ? ti0 : (j == 1 ? ti1 : (j == 2 ? ti2 : ti3)), 1);
        if (d < td3) {
            if (d < td2) {
                td3 = td2; ti3 = ti2;
                if (d < td1) {
                    td2 = td1; ti2 = ti1;
                    if (d < td0) { td1 = td0; ti1 = ti0; td0 = d; ti0 = bin; }
                    else { td1 = d; ti1 = bin; }
                } else { td2 = d; ti2 = bin; }
            } else { td3 = d; ti3 = bin; }
        }
    }
    if (h == 0) {
        size_t g = ((size_t)panel * 128 + row2) * 64 + T * 4;
        partD[g + 0] = td0; partI[g + 0] = ti0;
        partD[g + 1] = td1; partI[g + 1] = ti1;
        partD[g + 2] = td2; partI[g + 2] = ti2;
        partD[g + 3] = td3; partI[g + 3] = ti3;
    }
}

// ---------------------------------------------------------------------------
// fused phase-2 (r21): one wave per row; wave-cooperative rescore, batch-2
// slots (6 blocks/CU). r21 delta: the bit-exact chain reads LDS via explicit
// float4 (256 ds_read_b128 instead of up to 1024 ds_read_b32) -- same fmaf
// sequence, only load widths change.
__global__ __launch_bounds__(256, 6) void k_ru(const float* __restrict__ partD,
                                               const int* __restrict__ partI,
                                               float* __restrict__ resid,      // in/out (== quant region)
                                               float* __restrict__ rsq,        // in/out
                                               const float* __restrict__ csq,  // stage [NBINS]
                                               const float* __restrict__ cb,   // stage fp32
                                               float* __restrict__ codeOut,
                                               unsigned char* __restrict__ a8,
                                               float* __restrict__ sclr,
                                               const float* __restrict__ hidden,
                                               int last) {
    const int w = threadIdx.x >> 6;
    const int lane = threadIdx.x & 63;
    const int row = blockIdx.x * 4 + w;
    __shared__ float shbuf[4][DIM];          // pre-update resid row; reused as sq after
    __shared__ float crow[4][2][CSLOT];      // 2 candidate slots per wave

    const float* rp = resid + (size_t)row * DIM;
    float4 r0 = *(const float4*)(rp + lane * 8);
    float4 r1 = *(const float4*)(rp + lane * 8 + 4);
    *(float4*)&shbuf[w][lane * 8] = r0;
    *(float4*)&shbuf[w][lane * 8 + 4] = r1;

    // argmin resolve (validated margin path)
    float d = partD[(size_t)row * 64 + lane];
    int bi0 = partI[(size_t)row * 64 + lane];
    float bd = d; int bix = bi0;
#pragma unroll
    for (int o = 32; o > 0; o >>= 1) {
        float od = __shfl_xor(bd, o);
        int oi = __shfl_xor(bix, o);
        if (od < bd || (od == bd && oi < bix)) { bd = od; bix = oi; }
    }
    bool cand = (d <= bd + MARGIN);
    unsigned long long mask = __ballot(cand);
    int winI;
    if (__popcll(mask) == 1) {
        winI = bix;
    } else {
        float myD = 3.4e38f; int myI = 0x7fffffff;
        unsigned long long rem = mask;
        while (rem) {                        // wave-uniform loop, 2 candidates/pass
            int s0 = __ffsll(rem) - 1; rem &= rem - 1;
            int s1 = -1;
            if (rem) { s1 = __ffsll(rem) - 1; rem &= rem - 1; }

            {
                int cb0 = __shfl(bi0, s0);
                const float* cp = cb + (size_t)cb0 * DIM + lane * 8;
                *(float4*)&crow[w][0][lane * 8] = *(const float4*)cp;
                *(float4*)&crow[w][0][lane * 8 + 4] = *(const float4*)(cp + 4);
            }
            if (s1 >= 0) {
                int cb1 = __shfl(bi0, s1);
                const float* cp = cb + (size_t)cb1 * DIM + lane * 8;
                *(float4*)&crow[w][1][lane * 8] = *(const float4*)cp;
                *(float4*)&crow[w][1][lane * 8 + 4] = *(const float4*)(cp + 4);
            }
            asm volatile("s_waitcnt lgkmcnt(0)" ::: "memory");
            __builtin_amdgcn_sched_barrier(0);

            int myslot = (lane == s0) ? 0 : (lane == s1) ? 1 : -1;
            if (myslot >= 0) {
                const float* rr = shbuf[w];
                const float* cr = crow[w][myslot];
                float acc = 0.0f;
                for (int k = 0; k < DIM; k += 4) {    // bit-exact sequential chain,
                    float4 rv = *(const float4*)(rr + k);   // explicit b128 LDS reads
                    float4 cv = *(const float4*)(cr + k);
                    acc = fmaf(rv.x, cv.x, acc);
                    acc = fmaf(rv.y, cv.y, acc);
                    acc = fmaf(rv.z, cv.z, acc);
                    acc = fmaf(rv.w, cv.w, acc);
                }
                myD = __fadd_rn(__fsub_rn(rsq[row], __fmul_rn(2.0f, acc)), csq[bi0]);
                myI = bi0;
            }
            __builtin_amdgcn_sched_barrier(0);   // keep next batch's writes after reads
        }
#pragma unroll
        for (int o = 32; o > 0; o >>= 1) {
            float od = __shfl_xor(myD, o);
            int oi = __shfl_xor(myI, o);
            if (od < myD || (od == myD && oi < myI)) { myD = od; myI = oi; }
        }
        winI = myI;
    }
    if (lane == 0) codeOut[row] = (float)winI;
    const int id = winI;

    // exact fp32 residual update (validated round 4), 8 floats/lane
    const float* cp8 = cb + (size_t)id * DIM + lane * 8;
    float4 c0 = *(const float4*)cp8;
    float4 c1 = *(const float4*)(cp8 + 4);
    r0.x = __fsub_rn(r0.x, c0.x);
    r0.y = __fsub_rn(r0.y, c0.y);
    r0.z = __fsub_rn(r0.z, c0.z);
    r0.w = __fsub_rn(r0.w, c0.w);
    r1.x = __fsub_rn(r1.x, c1.x);
    r1.y = __fsub_rn(r1.y, c1.y);
    r1.z = __fsub_rn(r1.z, c1.z);
    r1.w = __fsub_rn(r1.w, c1.w);

    float* wp = resid + (size_t)row * DIM + lane * 8;
    if (last) {
        const float* hp = hidden + (size_t)row * DIM + lane * 8;
        float4 h0 = *(const float4*)hp;
        float4 h1 = *(const float4*)(hp + 4);
        float4 q0, q1;
        q0.x = __fsub_rn(h0.x, r0.x);
        q0.y = __fsub_rn(h0.y, r0.y);
        q0.z = __fsub_rn(h0.z, r0.z);
        q0.w = __fsub_rn(h0.w, r0.w);
        q1.x = __fsub_rn(h1.x, r1.x);
        q1.y = __fsub_rn(h1.y, r1.y);
        q1.z = __fsub_rn(h1.z, r1.z);
        q1.w = __fsub_rn(h1.w, r1.w);
        *(float4*)wp = q0;
        *(float4*)(wp + 4) = q1;
        return;   // uniform branch: all waves exit before the barrier
    }

    *(float4*)wp = r0;
    *(float4*)(wp + 4) = r1;

    // per-row i8 quantize for the next stage's MFMA
    float mx = fmaxf(fmaxf(fmaxf(fabsf(r0.x), fabsf(r0.y)), fmaxf(fabsf(r0.z), fabsf(r0.w))),
                     fmaxf(fmaxf(fabsf(r1.x), fabsf(r1.y)), fmaxf(fabsf(r1.z), fabsf(r1.w))));
#pragma unroll
    for (int m2 = 32; m2 > 0; m2 >>= 1) mx = fmaxf(mx, __shfl_xor(mx, m2));
    float qs = (mx > 0.0f) ? 127.0f / mx : 0.0f;
    int2 pv;
    pv.x = pack4(r0.x, r0.y, r0.z, r0.w, qs);
    pv.y = pack4(r1.x, r1.y, r1.z, r1.w, qs);
    *(int2*)(a8 + (size_t)row * DIM + lane * 8) = pv;
    if (lane == 0) sclr[row] = (mx > 0.0f) ? mx / 127.0f : 0.0f;

    // np-exact rsq: reuse shbuf[w] (own-wave rescore reads are complete)
    shbuf[w][lane * 8 + 0] = __fmul_rn(r0.x, r0.x);
    shbuf[w][lane * 8 + 1] = __fmul_rn(r0.y, r0.y);
    shbuf[w][lane * 8 + 2] = __fmul_rn(r0.z, r0.z);
    shbuf[w][lane * 8 + 3] = __fmul_rn(r0.w, r0.w);
    shbuf[w][lane * 8 + 4] = __fmul_rn(r1.x, r1.x);
    shbuf[w][lane * 8 + 5] = __fmul_rn(r1.y, r1.y);
    shbuf[w][lane * 8 + 6] = __fmul_rn(r1.z, r1.z);
    shbuf[w][lane * 8 + 7] = __fmul_rn(r1.w, r1.w);
    __syncthreads();
    if (lane < 32) {
        int base = (lane >> 3) * 128 + (lane & 7);
        float s = shbuf[w][base];
#pragma unroll
        for (int m = 1; m < 16; ++m) s = __fadd_rn(s, shbuf[w][base + 8 * m]);
        s = pw_combine(s);
        if (lane == 0) rsq[row] = s;
    }
}

// ---------------------------------------------------------------------------
extern "C" void kernel_launch(void* const* d_in, const int* in_sizes, int n_in,
                              void* d_out, int out_size, void* d_ws, size_t ws_size,
                              hipStream_t stream) {
    const float* hidden = (const float*)d_in[0];   // [NROWS][DIM]
    const float* cbs = (const float*)d_in[1];      // [NQ][NBINS][DIM]

    float* out_codes = (float*)d_out;                          // [NQ][NROWS]
    float* resid = out_codes + (size_t)NQ * NROWS;             // quant region doubles as residual

    // workspace (~41 MB)
    unsigned char* A8 = (unsigned char*)d_ws;                  // NROWS*DIM i8 (16MB)
    unsigned char* Cb8 = A8 + (size_t)NROWS * DIM;             // NQ*NBINS*DIM i8 (8MB)
    float* csq32 = (float*)(Cb8 + (size_t)NQ * NBINS * DIM);   // NQ*NBINS
    float* sclc = csq32 + (size_t)NQ * NBINS;                  // NQ*NBINS
    float* sclr = sclc + (size_t)NQ * NBINS;                   // NROWS
    float* rsq = sclr + NROWS;                                 // NROWS
    float* partD = rsq + NROWS;                                // NROWS*64
    int* partI = (int*)(partD + (size_t)NROWS * 64);           // NROWS*64

    k_prep<<<NQ * NBINS / 4, 256, 0, stream>>>(cbs, Cb8, csq32, sclc);
    k_init<<<NROWS / 4, 256, 0, stream>>>(hidden, resid, rsq, A8, sclr);

    for (int s = 0; s < NQ; ++s) {
        const float* cbS = cbs + (size_t)s * NBINS * DIM;
        k_gemm<<<(NROWS / 128) * (NBINS / 128), 256, 0, stream>>>(
            A8, Cb8 + (size_t)s * NBINS * DIM, csq32 + (size_t)s * NBINS,
            sclr, sclc + (size_t)s * NBINS, partD, partI);
        k_ru<<<NROWS / 4, 256, 0, stream>>>(partD, partI, resid, rsq,
                                            csq32 + (size_t)s * NBINS, cbS,
                                            out_codes + (size_t)s * NROWS, A8, sclr,
                                            hidden, s == NQ - 1);
    }
}

// Round 22
// 1108.059 us; speedup vs baseline: 1.0471x; 1.0471x over previous
//
#include <hip/hip_runtime.h>
#include <hip/hip_bf16.h>

#define NROWS 32768
#define DIM   512
#define NQ    8
#define NBINS 2048

#define MARGIN 5.0f        // ~7 sigma of i8 phase-1 dist-DIFF noise (validated r18-r20)
#define CSLOT  520         // floats per candidate LDS slot (bank offset 8 per slot)

typedef __attribute__((ext_vector_type(4))) float f32x4;
typedef __attribute__((ext_vector_type(4))) int i32x4;

typedef __attribute__((address_space(3))) void lds_t;
typedef __attribute__((address_space(1))) const void gbl_t;
__device__ inline void gload16(const void* g, void* l) {
    __builtin_amdgcn_global_load_lds((gbl_t*)g, (lds_t*)l, 16, 0, 0);
}

// ---------------------------------------------------------------------------
// numpy pairwise-sum combine (validated round 4)
__device__ inline float pw_combine(float s) {
#pragma unroll
    for (int m = 1; m <= 16; m <<= 1) {
        float o = __shfl_xor(s, m, 64);
        s = __fadd_rn(s, o);
    }
    return s;
}

// deterministic f32 -> i8 (RNE, clamp +-127), packed low byte
__device__ inline int q8(float v, float qs) {
    float x = fminf(fmaxf(v * qs, -127.0f), 127.0f);
    return __float2int_rn(x) & 255;
}
__device__ inline int pack4(float a, float b, float c, float d, float qs) {
    return q8(a, qs) | (q8(b, qs) << 8) | (q8(c, qs) << 16) | (q8(d, qs) << 24);
}

// ---------------------------------------------------------------------------
// fused prep: codebook fp32 -> i8 (per-bin scale) AND np-exact csq (validated r4/r16).
__global__ __launch_bounds__(256) void k_prep(const float* __restrict__ cb,
                                              unsigned char* __restrict__ o,
                                              float* __restrict__ csq32,
                                              float* __restrict__ sclc) {
    int row = blockIdx.x * 4 + (threadIdx.x >> 6);
    int lane = threadIdx.x & 63;
    const float* cp = cb + (size_t)row * DIM;

    float4 a = *(const float4*)(cp + lane * 8);
    float4 b = *(const float4*)(cp + lane * 8 + 4);

    float mx = fmaxf(fmaxf(fmaxf(fabsf(a.x), fabsf(a.y)), fmaxf(fabsf(a.z), fabsf(a.w))),
                     fmaxf(fmaxf(fabsf(b.x), fabsf(b.y)), fmaxf(fabsf(b.z), fabsf(b.w))));
#pragma unroll
    for (int m2 = 32; m2 > 0; m2 >>= 1) mx = fmaxf(mx, __shfl_xor(mx, m2));
    float qs = (mx > 0.0f) ? 127.0f / mx : 0.0f;

    int2 pv;
    pv.x = pack4(a.x, a.y, a.z, a.w, qs);
    pv.y = pack4(b.x, b.y, b.z, b.w, qs);
    *(int2*)(o + (size_t)row * DIM + lane * 8) = pv;

    float s = 0.0f;
    if (lane < 32) {
        int base = (lane >> 3) * 128 + (lane & 7);
        float e = cp[base];
        s = __fmul_rn(e, e);
#pragma unroll
        for (int m = 1; m < 16; ++m) {
            float e2 = cp[base + 8 * m];
            s = __fadd_rn(s, __fmul_rn(e2, e2));
        }
    }
    s = pw_combine(s);
    if (lane == 0) {
        csq32[row] = s;
        sclc[row] = (mx > 0.0f) ? mx / 127.0f : 0.0f;
    }
}

// ---------------------------------------------------------------------------
// initial residual (= hidden) + np-exact rsq + i8 copy (per-row scale).
__global__ __launch_bounds__(256) void k_init(const float* __restrict__ h,
                                              float* __restrict__ rout,
                                              float* __restrict__ rsq,
                                              unsigned char* __restrict__ a8,
                                              float* __restrict__ sclr) {
    int row = blockIdx.x * 4 + (threadIdx.x >> 6);
    int w = threadIdx.x >> 6;
    int lane = threadIdx.x & 63;
    __shared__ float sq[4][DIM];

    const float* hp = h + (size_t)row * DIM + lane * 8;
    float4 r0 = *(const float4*)hp;
    float4 r1 = *(const float4*)(hp + 4);
    float* wp = rout + (size_t)row * DIM + lane * 8;
    *(float4*)wp = r0;
    *(float4*)(wp + 4) = r1;

    float mx = fmaxf(fmaxf(fmaxf(fabsf(r0.x), fabsf(r0.y)), fmaxf(fabsf(r0.z), fabsf(r0.w))),
                     fmaxf(fmaxf(fabsf(r1.x), fabsf(r1.y)), fmaxf(fabsf(r1.z), fabsf(r1.w))));
#pragma unroll
    for (int m2 = 32; m2 > 0; m2 >>= 1) mx = fmaxf(mx, __shfl_xor(mx, m2));
    float qs = (mx > 0.0f) ? 127.0f / mx : 0.0f;
    int2 pv;
    pv.x = pack4(r0.x, r0.y, r0.z, r0.w, qs);
    pv.y = pack4(r1.x, r1.y, r1.z, r1.w, qs);
    *(int2*)(a8 + (size_t)row * DIM + lane * 8) = pv;
    if (lane == 0) sclr[row] = (mx > 0.0f) ? mx / 127.0f : 0.0f;

    sq[w][lane * 8 + 0] = __fmul_rn(r0.x, r0.x);
    sq[w][lane * 8 + 1] = __fmul_rn(r0.y, r0.y);
    sq[w][lane * 8 + 2] = __fmul_rn(r0.z, r0.z);
    sq[w][lane * 8 + 3] = __fmul_rn(r0.w, r0.w);
    sq[w][lane * 8 + 4] = __fmul_rn(r1.x, r1.x);
    sq[w][lane * 8 + 5] = __fmul_rn(r1.y, r1.y);
    sq[w][lane * 8 + 6] = __fmul_rn(r1.z, r1.z);
    sq[w][lane * 8 + 7] = __fmul_rn(r1.w, r1.w);
    __syncthreads();
    if (lane < 32) {
        int base = (lane >> 3) * 128 + (lane & 7);
        float s = sq[w][base];
#pragma unroll
        for (int m = 1; m < 16; ++m) s = __fadd_rn(s, sq[w][base + 8 * m]);
        s = pw_combine(s);
        if (lane == 0) rsq[row] = s;
    }
}

// ---------------------------------------------------------------------------
// phase-1: i8 MFMA GEMM (r16-validated math/layout, r19 dbuf staging).
// r20 epilogue: stride-68 dist tile (16B-aligned rows), float4 scan reads
// (conflict-free: x17 bijective mod 32), register-hoisted csq/sclc/sclr.
__global__ __launch_bounds__(256, 4) void k_gemm(const unsigned char* __restrict__ A8,
                                                 const unsigned char* __restrict__ B8,
                                                 const float* __restrict__ csq,
                                                 const float* __restrict__ sclr,
                                                 const float* __restrict__ sclc,
                                                 float* __restrict__ partD,   // [NROWS][64]
                                                 int* __restrict__ partI) {
    __shared__ __align__(16) char lds[34816];   // dbuf 2x(A8K|B8K)=32K ; dist [128][68] f32
    __shared__ float csqS[128], sclcS[128], sclrS[128];

    const int tid = threadIdx.x;
    const int lane = tid & 63;
    const int w = tid >> 6;
    const int wr = w >> 1;
    const int wc = w & 1;

    // L2-chunked XCD decode (validated r15/r16)
    const int wg = blockIdx.x;
    const int seq = wg >> 3;
    const int panel = (wg & 7) * 32 + (seq >> 8) * 16 + (seq & 15);
    const int T = (seq >> 4) & 15;

    if (tid < 128) {
        csqS[tid] = csq[T * 128 + tid];
        sclcS[tid] = sclc[T * 128 + tid];
        sclrS[tid] = sclr[panel * 128 + tid];
    }

    const char* Abase = (const char*)(A8 + (size_t)panel * 128 * DIM);
    const char* Bbase = (const char*)(B8 + (size_t)T * 128 * DIM);

    int goff[2], loff[2];
#pragma unroll
    for (int i = 0; i < 2; ++i) {
        int L = i * 256 + tid;
        int row = L >> 2, cc = L & 3;
        goff[i] = row * DIM + ((cc ^ ((row >> 1) & 3)) << 4);
        loff[i] = L * 16;
    }

    i32x4 acc[4][4];
#pragma unroll
    for (int m = 0; m < 4; ++m)
#pragma unroll
        for (int n = 0; n < 4; ++n) acc[m][n] = (i32x4){0, 0, 0, 0};

    const int arow = lane & 15;
    const int slot = ((lane >> 4) ^ ((arow >> 1) & 3)) << 4;

    // prologue: stage tile 0 into buf 0
#pragma unroll
    for (int i = 0; i < 2; ++i) {
        gload16(Abase + goff[i], lds + loff[i]);
        gload16(Bbase + goff[i], lds + 8192 + loff[i]);
    }
    __syncthreads();

#pragma unroll
    for (int ks = 0; ks < 8; ++ks) {
        if (ks < 7) {                          // issue next tile early (flies under MFMA)
            char* buf = lds + ((ks + 1) & 1) * 16384;
            const int k0b = (ks + 1) * 64;
#pragma unroll
            for (int i = 0; i < 2; ++i) {
                gload16(Abase + goff[i] + k0b, buf + loff[i]);
                gload16(Bbase + goff[i] + k0b, buf + 8192 + loff[i]);
            }
        }
        const char* Ab = lds + (ks & 1) * 16384;
        const char* Bb = Ab + 8192;
        __builtin_amdgcn_s_setprio(1);
        i32x4 bF[4];
#pragma unroll
        for (int n = 0; n < 4; ++n)
            bF[n] = *(const i32x4*)(Bb + (wc * 64 + n * 16 + arow) * 64 + slot);
#pragma unroll
        for (int m = 0; m < 4; ++m) {
            i32x4 aF = *(const i32x4*)(Ab + (wr * 64 + m * 16 + arow) * 64 + slot);
#pragma unroll
            for (int n = 0; n < 4; ++n)
                acc[m][n] = __builtin_amdgcn_mfma_i32_16x16x64_i8(
                    aF, bF[n], acc[m][n], 0, 0, 0);
        }
        __builtin_amdgcn_s_setprio(0);
        __syncthreads();   // tile ks reads done by all waves + tile ks+1 resident
    }

    // --- r20 epilogue (validated) ---
    float* distf = (float*)lds;
    const int row2 = tid >> 1, h = tid & 1;

    float rowsc[16];
#pragma unroll
    for (int m = 0; m < 4; ++m)
#pragma unroll
        for (int r = 0; r < 4; ++r)
            rowsc[m * 4 + r] = 2.0f * sclrS[wr * 64 + m * 16 + (lane >> 4) * 4 + r];

    float td0 = 3.4e38f, td1 = 3.4e38f, td2 = 3.4e38f, td3 = 3.4e38f;
    int ti0 = 0, ti1 = 0, ti2 = 0, ti3 = 0;

#pragma unroll
    for (int p = 0; p < 2; ++p) {
        float csq4[4], sclc4[4];
#pragma unroll
        for (int n = 0; n < 4; ++n) {
            csq4[n] = csqS[p * 64 + n * 16 + (lane & 15)];
            sclc4[n] = sclcS[p * 64 + n * 16 + (lane & 15)];
        }
        __syncthreads();
        if (wc == p) {
#pragma unroll
            for (int m = 0; m < 4; ++m)
#pragma unroll
                for (int n = 0; n < 4; ++n)
#pragma unroll
                    for (int r = 0; r < 4; ++r) {
                        int row = wr * 64 + m * 16 + (lane >> 4) * 4 + r;
                        int cl = n * 16 + (lane & 15);
                        distf[row * 68 + cl] =
                            csq4[n] - (float)acc[m][n][r] * (rowsc[m * 4 + r] * sclc4[n]);
                    }
        }
        __syncthreads();
        int binb = T * 128 + p * 64 + h * 32;
        const float* rowp = &distf[row2 * 68 + h * 32];
#pragma unroll
        for (int c4 = 0; c4 < 8; ++c4) {
            float4 v = *(const float4*)(rowp + c4 * 4);
#pragma unroll
            for (int j = 0; j < 4; ++j) {
                float d = (j == 0) ? v.x : (j == 1) ? v.y : (j == 2) ? v.z : v.w;
                int bin = binb + c4 * 4 + j;
                if (d < td3) {
                    if (d < td2) {
                        td3 = td2; ti3 = ti2;
                        if (d < td1) {
                            td2 = td1; ti2 = ti1;
                            if (d < td0) { td1 = td0; ti1 = ti0; td0 = d; ti0 = bin; }
                            else { td1 = d; ti1 = bin; }
                        } else { td2 = d; ti2 = bin; }
                    } else { td3 = d; ti3 = bin; }
                }
            }
        }
    }
#pragma unroll
    for (int j = 0; j < 4; ++j) {
        float d = __shfl_xor(j == 0 ? td0 : (j == 1 ? td1 : (j == 2 ? td2 : td3)), 1);
        int bin = __shfl_xor(j == 0 ? ti0 : (j == 1 ? ti1 : (j == 2 ? ti2 : ti3)), 1);
        if (d < td3) {
            if (d < td2) {
                td3 = td2; ti3 = ti2;
                if (d < td1) {
                    td2 = td1; ti2 = ti1;
                    if (d < td0) { td1 = td0; ti1 = ti0; td0 = d; ti0 = bin; }
                    else { td1 = d; ti1 = bin; }
                } else { td2 = d; ti2 = bin; }
            } else { td3 = d; ti3 = bin; }
        }
    }
    if (h == 0) {
        size_t g = ((size_t)panel * 128 + row2) * 64 + T * 4;
        partD[g + 0] = td0; partI[g + 0] = ti0;
        partD[g + 1] = td1; partI[g + 1] = ti1;
        partD[g + 2] = td2; partI[g + 2] = ti2;
        partD[g + 3] = td3; partI[g + 3] = ti3;
    }
}

// ---------------------------------------------------------------------------
// fused phase-2 (validated r18-r20): one wave per row; wave-cooperative
// rescore with batch-2 candidate slots (6 blocks/CU); scalar-indexed
// bit-exact chain (r21's float4 variant regressed -- reverted).
__global__ __launch_bounds__(256, 6) void k_ru(const float* __restrict__ partD,
                                               const int* __restrict__ partI,
                                               float* __restrict__ resid,      // in/out (== quant region)
                                               float* __restrict__ rsq,        // in/out
                                               const float* __restrict__ csq,  // stage [NBINS]
                                               const float* __restrict__ cb,   // stage fp32
                                               float* __restrict__ codeOut,
                                               unsigned char* __restrict__ a8,
                                               float* __restrict__ sclr,
                                               const float* __restrict__ hidden,
                                               int last) {
    const int w = threadIdx.x >> 6;
    const int lane = threadIdx.x & 63;
    const int row = blockIdx.x * 4 + w;
    __shared__ float shbuf[4][DIM];          // pre-update resid row; reused as sq after
    __shared__ float crow[4][2][CSLOT];      // 2 candidate slots per wave

    const float* rp = resid + (size_t)row * DIM;
    float4 r0 = *(const float4*)(rp + lane * 8);
    float4 r1 = *(const float4*)(rp + lane * 8 + 4);
    *(float4*)&shbuf[w][lane * 8] = r0;
    *(float4*)&shbuf[w][lane * 8 + 4] = r1;

    // argmin resolve (validated margin path)
    float d = partD[(size_t)row * 64 + lane];
    int bi0 = partI[(size_t)row * 64 + lane];
    float bd = d; int bix = bi0;
#pragma unroll
    for (int o = 32; o > 0; o >>= 1) {
        float od = __shfl_xor(bd, o);
        int oi = __shfl_xor(bix, o);
        if (od < bd || (od == bd && oi < bix)) { bd = od; bix = oi; }
    }
    bool cand = (d <= bd + MARGIN);
    unsigned long long mask = __ballot(cand);
    int winI;
    if (__popcll(mask) == 1) {
        winI = bix;
    } else {
        float myD = 3.4e38f; int myI = 0x7fffffff;
        unsigned long long rem = mask;
        while (rem) {                        // wave-uniform loop, 2 candidates/pass
            int s0 = __ffsll(rem) - 1; rem &= rem - 1;
            int s1 = -1;
            if (rem) { s1 = __ffsll(rem) - 1; rem &= rem - 1; }

            {
                int cb0 = __shfl(bi0, s0);
                const float* cp = cb + (size_t)cb0 * DIM + lane * 8;
                *(float4*)&crow[w][0][lane * 8] = *(const float4*)cp;
                *(float4*)&crow[w][0][lane * 8 + 4] = *(const float4*)(cp + 4);
            }
            if (s1 >= 0) {
                int cb1 = __shfl(bi0, s1);
                const float* cp = cb + (size_t)cb1 * DIM + lane * 8;
                *(float4*)&crow[w][1][lane * 8] = *(const float4*)cp;
                *(float4*)&crow[w][1][lane * 8 + 4] = *(const float4*)(cp + 4);
            }
            asm volatile("s_waitcnt lgkmcnt(0)" ::: "memory");
            __builtin_amdgcn_sched_barrier(0);

            int myslot = (lane == s0) ? 0 : (lane == s1) ? 1 : -1;
            if (myslot >= 0) {
                const float* rr = shbuf[w];
                const float* cr = crow[w][myslot];
                float acc = 0.0f;
                for (int k = 0; k < DIM; k += 4) {    // bit-exact sequential chain
                    acc = fmaf(rr[k + 0], cr[k + 0], acc);
                    acc = fmaf(rr[k + 1], cr[k + 1], acc);
                    acc = fmaf(rr[k + 2], cr[k + 2], acc);
                    acc = fmaf(rr[k + 3], cr[k + 3], acc);
                }
                myD = __fadd_rn(__fsub_rn(rsq[row], __fmul_rn(2.0f, acc)), csq[bi0]);
                myI = bi0;
            }
            __builtin_amdgcn_sched_barrier(0);   // keep next batch's writes after reads
        }
#pragma unroll
        for (int o = 32; o > 0; o >>= 1) {
            float od = __shfl_xor(myD, o);
            int oi = __shfl_xor(myI, o);
            if (od < myD || (od == myD && oi < myI)) { myD = od; myI = oi; }
        }
        winI = myI;
    }
    if (lane == 0) codeOut[row] = (float)winI;
    const int id = winI;

    // exact fp32 residual update (validated round 4), 8 floats/lane
    const float* cp8 = cb + (size_t)id * DIM + lane * 8;
    float4 c0 = *(const float4*)cp8;
    float4 c1 = *(const float4*)(cp8 + 4);
    r0.x = __fsub_rn(r0.x, c0.x);
    r0.y = __fsub_rn(r0.y, c0.y);
    r0.z = __fsub_rn(r0.z, c0.z);
    r0.w = __fsub_rn(r0.w, c0.w);
    r1.x = __fsub_rn(r1.x, c1.x);
    r1.y = __fsub_rn(r1.y, c1.y);
    r1.z = __fsub_rn(r1.z, c1.z);
    r1.w = __fsub_rn(r1.w, c1.w);

    float* wp = resid + (size_t)row * DIM + lane * 8;
    if (last) {
        const float* hp = hidden + (size_t)row * DIM + lane * 8;
        float4 h0 = *(const float4*)hp;
        float4 h1 = *(const float4*)(hp + 4);
        float4 q0, q1;
        q0.x = __fsub_rn(h0.x, r0.x);
        q0.y = __fsub_rn(h0.y, r0.y);
        q0.z = __fsub_rn(h0.z, r0.z);
        q0.w = __fsub_rn(h0.w, r0.w);
        q1.x = __fsub_rn(h1.x, r1.x);
        q1.y = __fsub_rn(h1.y, r1.y);
        q1.z = __fsub_rn(h1.z, r1.z);
        q1.w = __fsub_rn(h1.w, r1.w);
        *(float4*)wp = q0;
        *(float4*)(wp + 4) = q1;
        return;   // uniform branch: all waves exit before the barrier
    }

    *(float4*)wp = r0;
    *(float4*)(wp + 4) = r1;

    // per-row i8 quantize for the next stage's MFMA
    float mx = fmaxf(fmaxf(fmaxf(fabsf(r0.x), fabsf(r0.y)), fmaxf(fabsf(r0.z), fabsf(r0.w))),
                     fmaxf(fmaxf(fabsf(r1.x), fabsf(r1.y)), fmaxf(fabsf(r1.z), fabsf(r1.w))));
#pragma unroll
    for (int m2 = 32; m2 > 0; m2 >>= 1) mx = fmaxf(mx, __shfl_xor(mx, m2));
    float qs = (mx > 0.0f) ? 127.0f / mx : 0.0f;
    int2 pv;
    pv.x = pack4(r0.x, r0.y, r0.z, r0.w, qs);
    pv.y = pack4(r1.x, r1.y, r1.z, r1.w, qs);
    *(int2*)(a8 + (size_t)row * DIM + lane * 8) = pv;
    if (lane == 0) sclr[row] = (mx > 0.0f) ? mx / 127.0f : 0.0f;

    // np-exact rsq: reuse shbuf[w] (own-wave rescore reads are complete)
    shbuf[w][lane * 8 + 0] = __fmul_rn(r0.x, r0.x);
    shbuf[w][lane * 8 + 1] = __fmul_rn(r0.y, r0.y);
    shbuf[w][lane * 8 + 2] = __fmul_rn(r0.z, r0.z);
    shbuf[w][lane * 8 + 3] = __fmul_rn(r0.w, r0.w);
    shbuf[w][lane * 8 + 4] = __fmul_rn(r1.x, r1.x);
    shbuf[w][lane * 8 + 5] = __fmul_rn(r1.y, r1.y);
    shbuf[w][lane * 8 + 6] = __fmul_rn(r1.z, r1.z);
    shbuf[w][lane * 8 + 7] = __fmul_rn(r1.w, r1.w);
    __syncthreads();
    if (lane < 32) {
        int base = (lane >> 3) * 128 + (lane & 7);
        float s = shbuf[w][base];
#pragma unroll
        for (int m = 1; m < 16; ++m) s = __fadd_rn(s, shbuf[w][base + 8 * m]);
        s = pw_combine(s);
        if (lane == 0) rsq[row] = s;
    }
}

// ---------------------------------------------------------------------------
extern "C" void kernel_launch(void* const* d_in, const int* in_sizes, int n_in,
                              void* d_out, int out_size, void* d_ws, size_t ws_size,
                              hipStream_t stream) {
    const float* hidden = (const float*)d_in[0];   // [NROWS][DIM]
    const float* cbs = (const float*)d_in[1];      // [NQ][NBINS][DIM]

    float* out_codes = (float*)d_out;                          // [NQ][NROWS]
    float* resid = out_codes + (size_t)NQ * NROWS;             // quant region doubles as residual

    // workspace (~41 MB)
    unsigned char* A8 = (unsigned char*)d_ws;                  // NROWS*DIM i8 (16MB)
    unsigned char* Cb8 = A8 + (size_t)NROWS * DIM;             // NQ*NBINS*DIM i8 (8MB)
    float* csq32 = (float*)(Cb8 + (size_t)NQ * NBINS * DIM);   // NQ*NBINS
    float* sclc = csq32 + (size_t)NQ * NBINS;                  // NQ*NBINS
    float* sclr = sclc + (size_t)NQ * NBINS;                   // NROWS
    float* rsq = sclr + NROWS;                                 // NROWS
    float* partD = rsq + NROWS;                                // NROWS*64
    int* partI = (int*)(partD + (size_t)NROWS * 64);           // NROWS*64

    k_prep<<<NQ * NBINS / 4, 256, 0, stream>>>(cbs, Cb8, csq32, sclc);
    k_init<<<NROWS / 4, 256, 0, stream>>>(hidden, resid, rsq, A8, sclr);

    for (int s = 0; s < NQ; ++s) {
        const float* cbS = cbs + (size_t)s * NBINS * DIM;
        k_gemm<<<(NROWS / 128) * (NBINS / 128), 256, 0, stream>>>(
            A8, Cb8 + (size_t)s * NBINS * DIM, csq32 + (size_t)s * NBINS,
            sclr, sclc + (size_t)s * NBINS, partD, partI);
        k_ru<<<NROWS / 4, 256, 0, stream>>>(partD, partI, resid, rsq,
                                            csq32 + (size_t)s * NBINS, cbS,
                                            out_codes + (size_t)s * NROWS, A8, sclr,
                                            hidden, s == NQ - 1);
    }
}